// Round 1
// baseline (557.323 us; speedup 1.0000x reference)
//
#include <hip/hip_runtime.h>

#define B_ 64
#define N_ 2048
#define D_ 256
#define H_ 8
#define LARGE_ 1e9f
#define EPS_ 1e-10f

typedef __attribute__((ext_vector_type(4))) float f32x4;
typedef __attribute__((ext_vector_type(8))) short s16x8;

// workspace layout (bytes)
#define WS_QSUM   0          // 64*256 f32 = 65536
#define WS_MSUM   65536      // 64 f32
#define WS_WM     65792      // 64*8*256 f32 = 524288  (zeroed region ends at 590080)
#define WS_ZERO_BYTES 590080
#define WS_QK     655360     // 64*8*256 f32
#define WS_LOGITS 2097152    // 64*8*2048 f32 = 4 MB
#define WS_WGP    6291456    // 256*256 bf16 = 128 KB
#define WS_WPP    8388608    // 64*256*256 bf16 = 8 MB

__device__ __forceinline__ unsigned short f2bf(float f) {
  union { float f; unsigned u; } v; v.f = f;
  unsigned r = v.u + 0x7fffu + ((v.u >> 16) & 1u);
  return (unsigned short)(r >> 16);
}

// ---------------- KA: q_sum/mask_sum reduction (blocks 0..511) + Wg pack (512..575)
__global__ void kA(const float* __restrict__ q_data, const float* __restrict__ q_mask,
                   const float* __restrict__ gating_w, float* __restrict__ q_sum,
                   float* __restrict__ mask_sum, unsigned short* __restrict__ wgp) {
  int blk = blockIdx.x, t = threadIdx.x;
  if (blk < 512) {
    int b = blk >> 3, n0 = (blk & 7) * 256;
    __shared__ float msk[256];
    __shared__ float mred[4];
    msk[t] = q_mask[b * N_ + n0 + t];
    __syncthreads();
    const float* qp = q_data + ((size_t)b * N_ + n0) * D_ + t;
    float acc = 0.f;
    #pragma unroll 4
    for (int r = 0; r < 256; ++r) acc += msk[r] * qp[(size_t)r * D_];
    atomicAdd(&q_sum[b * D_ + t], acc);
    float mv = msk[t];
    for (int off = 32; off; off >>= 1) mv += __shfl_xor(mv, off);
    if ((t & 63) == 0) mred[t >> 6] = mv;
    __syncthreads();
    if (t == 0) atomicAdd(&mask_sum[b], mred[0] + mred[1] + mred[2] + mred[3]);
  } else {
    int base = (blk - 512) * 1024;
    for (int i = 0; i < 4; ++i) {
      int a = base + i * 256 + t;
      int sc = a >> 9, l = (a >> 3) & 63, j = a & 7;
      int s = sc >> 4, c = sc & 15, lh = l >> 4, ll = l & 15;
      int k = s * 32 + lh * 8 + j, n = c * 16 + ll;
      wgp[a] = f2bf(gating_w[k * 256 + n]);
    }
  }
}

// ---------------- KB: q_avg -> q -> qk  (one block per batch)
__global__ void kB(const float* __restrict__ q_sum, const float* __restrict__ mask_sum,
                   const float* __restrict__ query_w, const float* __restrict__ key_w,
                   float* __restrict__ qk) {
  int b = blockIdx.x, t = threadIdx.x;
  __shared__ float qa[256];
  __shared__ float ql[256];
  float inv = 1.f / (mask_sum[b] + EPS_);
  qa[t] = q_sum[b * 256 + t] * inv;
  __syncthreads();
  float s = 0.f;
  #pragma unroll 4
  for (int a = 0; a < 256; ++a) s += qa[a] * query_w[a * 256 + t];
  ql[t] = s * 0.17677669529663687f;  // * KD^-0.5
  __syncthreads();
  #pragma unroll
  for (int h = 0; h < 8; ++h) {
    float v = 0.f;
    #pragma unroll
    for (int c = 0; c < 32; ++c) v += key_w[t * 32 + c] * ql[h * 32 + c];
    qk[((size_t)b * 8 + h) * 256 + t] = v;
  }
}

// ---------------- KC: logits[b,h,n] = qk[b,h,:].m_data[b,n,:] + bias
__global__ void kC(const float* __restrict__ m_data, const float* __restrict__ q_mask,
                   const float* __restrict__ qk, float* __restrict__ logits) {
  int nt = blockIdx.x, b = blockIdx.y, t = threadIdx.x;
  __shared__ alignas(16) float qkl[8 * 256];
  #pragma unroll
  for (int i = 0; i < 8; ++i) qkl[i * 256 + t] = qk[((size_t)b * 8 + i) * 256 + t];
  __syncthreads();
  int n = nt * 256 + t;
  const float4* mp = (const float4*)(m_data + ((size_t)b * N_ + n) * D_);
  float acc[8] = {0.f, 0.f, 0.f, 0.f, 0.f, 0.f, 0.f, 0.f};
  #pragma unroll 2
  for (int k4 = 0; k4 < 64; ++k4) {
    float4 m4 = mp[k4];
    #pragma unroll
    for (int h = 0; h < 8; ++h) {
      float4 q4 = ((const float4*)(qkl + h * 256))[k4];
      acc[h] += m4.x * q4.x + m4.y * q4.y + m4.z * q4.z + m4.w * q4.w;
    }
  }
  float bias = LARGE_ * (q_mask[b * N_ + n] - 1.f);
  #pragma unroll
  for (int h = 0; h < 8; ++h) logits[((size_t)b * 8 + h) * N_ + n] = acc[h] + bias;
}

// ---------------- KE: softmax (recomputed per block) + wm partial accumulation
__global__ void kE(const float* __restrict__ m_data, const float* __restrict__ logits,
                   float* __restrict__ wm) {
  int nt = blockIdx.x, b = blockIdx.y, t = threadIdx.x;
  __shared__ float wl[8 * 256];
  __shared__ float red[4];
  for (int h = 0; h < 8; ++h) {
    const float* lp = logits + ((size_t)b * 8 + h) * N_;
    float lg[8];
    #pragma unroll
    for (int i = 0; i < 8; ++i) lg[i] = lp[i * 256 + t];
    float mx = lg[0];
    #pragma unroll
    for (int i = 1; i < 8; ++i) mx = fmaxf(mx, lg[i]);
    for (int off = 32; off; off >>= 1) mx = fmaxf(mx, __shfl_xor(mx, off));
    if ((t & 63) == 0) red[t >> 6] = mx;
    __syncthreads();
    mx = fmaxf(fmaxf(red[0], red[1]), fmaxf(red[2], red[3]));
    __syncthreads();
    float sm = 0.f;
    #pragma unroll
    for (int i = 0; i < 8; ++i) sm += __expf(lg[i] - mx);
    for (int off = 32; off; off >>= 1) sm += __shfl_xor(sm, off);
    if ((t & 63) == 0) red[t >> 6] = sm;
    __syncthreads();
    float rs = 1.f / (red[0] + red[1] + red[2] + red[3]);
    // this block's n-slice: reload (avoids dynamic reg-array index)
    wl[h * 256 + t] = __expf(lp[nt * 256 + t] - mx) * rs;
    __syncthreads();
  }
  float a8[8] = {0.f, 0.f, 0.f, 0.f, 0.f, 0.f, 0.f, 0.f};
  const float* mp = m_data + ((size_t)b * N_ + nt * 256) * D_ + t;
  #pragma unroll 2
  for (int r = 0; r < 256; ++r) {
    float mv = mp[(size_t)r * D_];
    #pragma unroll
    for (int h = 0; h < 8; ++h) a8[h] += wl[h * 256 + r] * mv;
  }
  #pragma unroll
  for (int h = 0; h < 8; ++h) atomicAdd(&wm[((size_t)b * 8 + h) * 256 + t], a8[h]);
}

// ---------------- KF: wa = wm @ value_w; pack W'[b] = diag(wa) * output_w (bf16, frag layout)
__global__ void kF(const float* __restrict__ wm, const float* __restrict__ value_w,
                   const float* __restrict__ output_w, unsigned short* __restrict__ wpp) {
  int blk = blockIdx.x, t = threadIdx.x;
  int b = blk >> 2, quad = blk & 3;
  __shared__ float wml[8 * 256];
  __shared__ float wa[256];
  #pragma unroll
  for (int i = 0; i < 8; ++i) wml[i * 256 + t] = wm[((size_t)b * 8 + i) * 256 + t];
  __syncthreads();
  {
    int h = t >> 5, v = t & 31;
    float s = 0.f;
    #pragma unroll 4
    for (int d = 0; d < 256; ++d) s += wml[h * 256 + d] * value_w[d * 32 + v];
    wa[t] = s;
  }
  __syncthreads();
  unsigned short* wp = wpp + (size_t)b * 65536;
  int base = quad * 16384;
  for (int it = 0; it < 64; ++it) {
    int a = base + it * 256 + t;
    int sc = a >> 9, l = (a >> 3) & 63, j = a & 7;
    int s = sc >> 4, c = sc & 15, lh = l >> 4, ll = l & 15;
    int hv = s * 32 + lh * 8 + j, o = c * 16 + ll;
    wp[a] = f2bf(wa[hv] * output_w[hv * 256 + o]);
  }
}

// ---------------- KG: out = sigmoid(q@Wg + gb) @ W'[b] + ob   (bf16 MFMA, fused)
__global__ void __launch_bounds__(512, 4) kG(
    const float* __restrict__ q_data, const float* __restrict__ gating_b,
    const float* __restrict__ output_b, const unsigned short* __restrict__ wgp,
    const unsigned short* __restrict__ wpp, float* __restrict__ out) {
  int b = blockIdx.y, row0 = blockIdx.x * 128, t = threadIdx.x;
  __shared__ unsigned char sA[65536];  // 128 rows x 256 k, bf16, fragment-ordered [k/8][m][j]
  {
    int m = t >> 2, sub = t & 3;
    const float* qp = q_data + ((size_t)b * N_ + row0 + m) * D_;
    #pragma unroll
    for (int i = 0; i < 16; ++i) {
      int k = i * 16 + sub * 4;
      float4 v = *(const float4*)(qp + k);
      uint2 pp;
      pp.x = f2bf(v.x) | ((unsigned)f2bf(v.y) << 16);
      pp.y = f2bf(v.z) | ((unsigned)f2bf(v.w) << 16);
      *(uint2*)(sA + (((k >> 3) * 128 + m) << 4) + (k & 7) * 2) = pp;
    }
  }
  __syncthreads();
  int lane = t & 63, w = t >> 6;
  int rg = w >> 2, cg = w & 3;            // 2 row-groups x 4 col-groups of 64x64
  int l15 = lane & 15, lhi = lane >> 4;
  const f32x4 z = {0.f, 0.f, 0.f, 0.f};
  f32x4 acc[16];
  #pragma unroll
  for (int f = 0; f < 16; ++f) acc[f] = z;
  const s16x8* Bg = (const s16x8*)wgp;
  #pragma unroll
  for (int s = 0; s < 8; ++s) {
    s16x8 af[4], bfr[4];
    #pragma unroll
    for (int rt = 0; rt < 4; ++rt)
      af[rt] = *(const s16x8*)(sA + ((((s * 4 + lhi) * 128) + rg * 64 + rt * 16 + l15) << 4));
    #pragma unroll
    for (int ct = 0; ct < 4; ++ct)
      bfr[ct] = Bg[(s * 16 + cg * 4 + ct) * 64 + lane];
    #pragma unroll
    for (int rt = 0; rt < 4; ++rt)
      #pragma unroll
      for (int ct = 0; ct < 4; ++ct)
        acc[rt * 4 + ct] =
            __builtin_amdgcn_mfma_f32_16x16x32_bf16(af[rt], bfr[ct], acc[rt * 4 + ct], 0, 0, 0);
  }
  __syncthreads();  // all waves done reading A
  {
    float gb[4];
    #pragma unroll
    for (int ct = 0; ct < 4; ++ct) gb[ct] = gating_b[cg * 64 + ct * 16 + l15];
    #pragma unroll
    for (int rt = 0; rt < 4; ++rt)
      #pragma unroll
      for (int ct = 0; ct < 4; ++ct) {
        int col = cg * 64 + ct * 16 + l15;
        #pragma unroll
        for (int r = 0; r < 4; ++r) {
          float x = acc[rt * 4 + ct][r] + gb[ct];
          float g = 1.f / (1.f + __expf(-x));
          int row = rg * 64 + rt * 16 + lhi * 4 + r;
          *(unsigned short*)(sA + (((col >> 3) * 128 + row) << 4) + (col & 7) * 2) = f2bf(g);
        }
      }
  }
  __syncthreads();  // G fully written
  #pragma unroll
  for (int f = 0; f < 16; ++f) acc[f] = z;
  const s16x8* Bp = (const s16x8*)wpp + (size_t)b * 8192;
  #pragma unroll
  for (int s = 0; s < 8; ++s) {
    s16x8 af[4], bfr[4];
    #pragma unroll
    for (int rt = 0; rt < 4; ++rt)
      af[rt] = *(const s16x8*)(sA + ((((s * 4 + lhi) * 128) + rg * 64 + rt * 16 + l15) << 4));
    #pragma unroll
    for (int ct = 0; ct < 4; ++ct)
      bfr[ct] = Bp[(s * 16 + cg * 4 + ct) * 64 + lane];
    #pragma unroll
    for (int rt = 0; rt < 4; ++rt)
      #pragma unroll
      for (int ct = 0; ct < 4; ++ct)
        acc[rt * 4 + ct] =
            __builtin_amdgcn_mfma_f32_16x16x32_bf16(af[rt], bfr[ct], acc[rt * 4 + ct], 0, 0, 0);
  }
  {
    float ob[4];
    #pragma unroll
    for (int ct = 0; ct < 4; ++ct) ob[ct] = output_b[cg * 64 + ct * 16 + l15];
    #pragma unroll
    for (int rt = 0; rt < 4; ++rt)
      #pragma unroll
      for (int ct = 0; ct < 4; ++ct) {
        int col = cg * 64 + ct * 16 + l15;
        #pragma unroll
        for (int r = 0; r < 4; ++r) {
          int row = rg * 64 + rt * 16 + lhi * 4 + r;
          out[((size_t)b * N_ + row0 + row) * 256 + col] = acc[rt * 4 + ct][r] + ob[ct];
        }
      }
  }
}

extern "C" void kernel_launch(void* const* d_in, const int* in_sizes, int n_in,
                              void* d_out, int out_size, void* d_ws, size_t ws_size,
                              hipStream_t stream) {
  const float* q_data  = (const float*)d_in[0];
  const float* m_data  = (const float*)d_in[1];
  const float* q_mask  = (const float*)d_in[2];
  const float* query_w = (const float*)d_in[3];
  const float* key_w   = (const float*)d_in[4];
  const float* value_w = (const float*)d_in[5];
  const float* gating_w = (const float*)d_in[6];
  const float* gating_b = (const float*)d_in[7];
  const float* output_w = (const float*)d_in[8];
  const float* output_b = (const float*)d_in[9];
  float* out = (float*)d_out;
  char* ws = (char*)d_ws;

  float* q_sum = (float*)(ws + WS_QSUM);
  float* msum  = (float*)(ws + WS_MSUM);
  float* wm    = (float*)(ws + WS_WM);
  float* qk    = (float*)(ws + WS_QK);
  float* logits = (float*)(ws + WS_LOGITS);
  unsigned short* wgp = (unsigned short*)(ws + WS_WGP);
  unsigned short* wpp = (unsigned short*)(ws + WS_WPP);

  hipMemsetAsync(d_ws, 0, WS_ZERO_BYTES, stream);
  kA<<<576, 256, 0, stream>>>(q_data, q_mask, gating_w, q_sum, msum, wgp);
  kB<<<64, 256, 0, stream>>>(q_sum, msum, query_w, key_w, qk);
  kC<<<dim3(8, 64), 256, 0, stream>>>(m_data, q_mask, qk, logits);
  kE<<<dim3(8, 64), 256, 0, stream>>>(m_data, logits, wm);
  kF<<<256, 256, 0, stream>>>(wm, value_w, output_w, wpp);
  kG<<<dim3(16, 64), 512, 0, stream>>>(q_data, gating_b, output_b, wgp, wpp, out);
}

// Round 2
// 511.240 us; speedup vs baseline: 1.0901x; 1.0901x over previous
//
#include <hip/hip_runtime.h>

#define B_ 64
#define N_ 2048
#define D_ 256
#define H_ 8
#define LARGE_ 1e9f
#define EPS_ 1e-10f

typedef __attribute__((ext_vector_type(4))) float f32x4;
typedef __attribute__((ext_vector_type(8))) short s16x8;

// workspace layout (bytes)
#define WS_QSUM 0          // 64*256 f32 = 65536
#define WS_MSUM 65536      // 64 f32 (zero region ends 65792)
#define WS_ZERO 65792
#define WS_QKBF 66048      // qk A-frag bf16: 64 b * 8 kblk * 64 lane * 8 = 524288
#define WS_LOG  590336     // logits/weights [b][n][8] f32 = 4194304
#define WS_WMP  4784640    // wm partials [b][8][256][8] bf16 = 2097152
#define WS_WGP  6881792    // gating_w pack bf16 = 131072
#define WS_WPP  7012864    // per-batch output pack bf16 = 8388608  (ends 15401472)

__device__ __forceinline__ unsigned short f2bf(float f) {
  union { float f; unsigned u; } v; v.f = f;
  unsigned r = v.u + 0x7fffu + ((v.u >> 16) & 1u);
  return (unsigned short)(r >> 16);
}
__device__ __forceinline__ float bf2f(unsigned short s) {
  union { unsigned u; float f; } v; v.u = ((unsigned)s) << 16;
  return v.f;
}

// ---------------- kA: coalesced masked q-sum reduction + Wg pack
__global__ void kA(const float* __restrict__ q_data, const float* __restrict__ q_mask,
                   const float* __restrict__ gating_w, float* __restrict__ q_sum,
                   float* __restrict__ mask_sum, unsigned short* __restrict__ wgp) {
  int blk = blockIdx.x, t = threadIdx.x;
  if (blk < 512) {
    int b = blk >> 3, n0 = (blk & 7) * 256;
    __shared__ float msk[256];
    __shared__ float mred[4];
    msk[t] = q_mask[b * N_ + n0 + t];
    __syncthreads();
    int w = t >> 6, d4 = t & 63;
    const float* qbase = q_data + ((size_t)(b * N_ + n0)) * D_;
    f32x4 acc = {0.f, 0.f, 0.f, 0.f};
    #pragma unroll 4
    for (int i = 0; i < 64; ++i) {
      int r = i * 4 + w;
      f32x4 v = *(const f32x4*)(qbase + (size_t)r * D_ + d4 * 4);
      float mk = msk[r];
      acc += v * mk;
    }
    float* qs = q_sum + b * D_ + d4 * 4;
    atomicAdd(qs + 0, acc[0]);
    atomicAdd(qs + 1, acc[1]);
    atomicAdd(qs + 2, acc[2]);
    atomicAdd(qs + 3, acc[3]);
    float mv = msk[t];
    for (int off = 32; off; off >>= 1) mv += __shfl_xor(mv, off);
    if ((t & 63) == 0) mred[t >> 6] = mv;
    __syncthreads();
    if (t == 0) atomicAdd(&mask_sum[b], mred[0] + mred[1] + mred[2] + mred[3]);
  } else {
    int base = (blk - 512) * 1024;
    for (int i = 0; i < 4; ++i) {
      int a = base + i * 256 + t;
      int sc = a >> 9, l = (a >> 3) & 63, j = a & 7;
      int s = sc >> 4, c = sc & 15, lh = l >> 4, ll = l & 15;
      int k = s * 32 + lh * 8 + j, n = c * 16 + ll;
      wgp[a] = f2bf(gating_w[k * 256 + n]);
    }
  }
}

// ---------------- kB: q_avg -> q -> qk, packed into bf16 A-fragment layout (M=16, heads 0..7)
__global__ void kB(const float* __restrict__ q_sum, const float* __restrict__ mask_sum,
                   const float* __restrict__ query_w, const float* __restrict__ key_w,
                   unsigned short* __restrict__ qkbf) {
  int b = blockIdx.x, t = threadIdx.x;
  __shared__ float qa[256];
  __shared__ float ql[256];
  float inv = 1.f / (mask_sum[b] + EPS_);
  qa[t] = q_sum[b * 256 + t] * inv;
  __syncthreads();
  float s = 0.f;
  #pragma unroll 4
  for (int a = 0; a < 256; ++a) s += qa[a] * query_w[a * 256 + t];
  ql[t] = s * 0.17677669529663687f;  // * KD^-0.5
  __syncthreads();
  float v8[8];
  #pragma unroll
  for (int h = 0; h < 8; ++h) {
    float v = 0.f;
    #pragma unroll
    for (int c = 0; c < 32; ++c) v += key_w[t * 32 + c] * ql[h * 32 + c];
    v8[h] = v;
  }
  int si = t >> 5, lh = (t >> 3) & 3, j = t & 7;
  unsigned short* base = qkbf + ((size_t)(b * 8 + si) * 64) * 8;
  #pragma unroll
  for (int h = 0; h < 8; ++h) {
    base[(lh * 16 + h) * 8 + j] = f2bf(v8[h]);
    base[(lh * 16 + 8 + h) * 8 + j] = 0;
  }
}

// ---------------- kC: logits[b,n,h] via MFMA (A=qk frag, B=m-tile from LDS)
__global__ void kC(const float* __restrict__ m_data, const float* __restrict__ q_mask,
                   const unsigned short* __restrict__ qkbf, float* __restrict__ logits) {
  int b = blockIdx.y, n0 = blockIdx.x * 64, t = threadIdx.x;
  __shared__ __align__(16) unsigned char sM[64 * 528];
  {
    int w = t >> 6, d4 = t & 63;
    #pragma unroll
    for (int i = 0; i < 16; ++i) {
      int r = i * 4 + w;
      f32x4 v = *(const f32x4*)(m_data + ((size_t)(b * N_ + n0 + r)) * D_ + d4 * 4);
      uint2 pp;
      pp.x = f2bf(v[0]) | ((unsigned)f2bf(v[1]) << 16);
      pp.y = f2bf(v[2]) | ((unsigned)f2bf(v[3]) << 16);
      *(uint2*)(sM + r * 528 + d4 * 8) = pp;
    }
  }
  __syncthreads();
  int lane = t & 63, w = t >> 6;
  int l15 = lane & 15, lhi = lane >> 4;
  const s16x8* A = (const s16x8*)qkbf + (size_t)b * 512;
  s16x8 areg[8];
  #pragma unroll
  for (int s = 0; s < 8; ++s) areg[s] = A[s * 64 + lane];
  f32x4 acc = {0.f, 0.f, 0.f, 0.f};
  int nrow = w * 16 + l15;
  #pragma unroll
  for (int s = 0; s < 8; ++s) {
    s16x8 bfr = *(const s16x8*)(sM + nrow * 528 + s * 64 + lhi * 16);
    acc = __builtin_amdgcn_mfma_f32_16x16x32_bf16(areg[s], bfr, acc, 0, 0, 0);
  }
  if (lhi < 2) {
    int n = n0 + nrow;
    float bias = LARGE_ * (q_mask[b * N_ + n] - 1.f);
    f32x4 st = acc + bias;
    *(f32x4*)(logits + ((size_t)(b * N_ + n)) * 8 + lhi * 4) = st;
  }
}

// ---------------- kS: softmax over n per (b,h), in-place on [b][n][8] buffer
__global__ void kS(float* __restrict__ wbuf) {
  int b = blockIdx.x, t = threadIdx.x;
  int lane = t & 63, w = t >> 6;
  __shared__ float sred[4][8];
  __shared__ float Mh[8];
  __shared__ float Sh[8];
  f32x4 lv[16];
  f32x4* base = (f32x4*)(wbuf + (size_t)b * N_ * 8) + t * 16;
  #pragma unroll
  for (int i = 0; i < 16; ++i) lv[i] = base[i];
  float pm[8];
  #pragma unroll
  for (int h = 0; h < 8; ++h) pm[h] = -3.4e38f;
  #pragma unroll
  for (int k = 0; k < 8; ++k)
    #pragma unroll
    for (int hh = 0; hh < 2; ++hh)
      #pragma unroll
      for (int c = 0; c < 4; ++c)
        pm[hh * 4 + c] = fmaxf(pm[hh * 4 + c], lv[k * 2 + hh][c]);
  for (int off = 32; off; off >>= 1)
    #pragma unroll
    for (int h = 0; h < 8; ++h) pm[h] = fmaxf(pm[h], __shfl_xor(pm[h], off));
  if (lane == 0)
    #pragma unroll
    for (int h = 0; h < 8; ++h) sred[w][h] = pm[h];
  __syncthreads();
  if (t < 8) Mh[t] = fmaxf(fmaxf(sred[0][t], sred[1][t]), fmaxf(sred[2][t], sred[3][t]));
  __syncthreads();
  float M[8], ps[8];
  #pragma unroll
  for (int h = 0; h < 8; ++h) { M[h] = Mh[h]; ps[h] = 0.f; }
  #pragma unroll
  for (int k = 0; k < 8; ++k)
    #pragma unroll
    for (int hh = 0; hh < 2; ++hh)
      #pragma unroll
      for (int c = 0; c < 4; ++c) {
        float e = __expf(lv[k * 2 + hh][c] - M[hh * 4 + c]);
        lv[k * 2 + hh][c] = e;
        ps[hh * 4 + c] += e;
      }
  for (int off = 32; off; off >>= 1)
    #pragma unroll
    for (int h = 0; h < 8; ++h) ps[h] += __shfl_xor(ps[h], off);
  if (lane == 0)
    #pragma unroll
    for (int h = 0; h < 8; ++h) sred[w][h] = ps[h];
  __syncthreads();
  if (t < 8) Sh[t] = sred[0][t] + sred[1][t] + sred[2][t] + sred[3][t];
  __syncthreads();
  float rs[8];
  #pragma unroll
  for (int h = 0; h < 8; ++h) rs[h] = 1.f / Sh[h];
  #pragma unroll
  for (int k = 0; k < 8; ++k)
    #pragma unroll
    for (int hh = 0; hh < 2; ++hh)
      #pragma unroll
      for (int c = 0; c < 4; ++c) lv[k * 2 + hh][c] *= rs[hh * 4 + c];
  #pragma unroll
  for (int i = 0; i < 16; ++i) base[i] = lv[i];
}

// ---------------- kE: weighted sum of m rows (fp32, coalesced, block partials -> bf16)
__global__ void kE(const float* __restrict__ m_data, const float* __restrict__ wbuf,
                   unsigned short* __restrict__ wm_part) {
  int b = blockIdx.y, n0 = blockIdx.x * 256, t = threadIdx.x;
  __shared__ float wb[2048];
  __shared__ float red[4 * 8 * 256];  // [w*8+h][256]
  {
    const f32x4* src = (const f32x4*)(wbuf + ((size_t)b * N_ + n0) * 8);
    f32x4* dst = (f32x4*)wb;
    dst[t] = src[t];
    dst[t + 256] = src[t + 256];
  }
  __syncthreads();
  int w = t >> 6, l = t & 63;
  f32x4 acc[8];
  #pragma unroll
  for (int h = 0; h < 8; ++h) acc[h] = (f32x4){0.f, 0.f, 0.f, 0.f};
  const float* mbase = m_data + ((size_t)(b * N_ + n0 + w * 64)) * D_ + l * 4;
  #pragma unroll 2
  for (int i = 0; i < 64; ++i) {
    f32x4 mv = *(const f32x4*)(mbase + (size_t)i * D_);
    const f32x4* wrow = (const f32x4*)(wb + (w * 64 + i) * 8);
    f32x4 w0 = wrow[0], w1 = wrow[1];
    acc[0] += mv * w0[0]; acc[1] += mv * w0[1]; acc[2] += mv * w0[2]; acc[3] += mv * w0[3];
    acc[4] += mv * w1[0]; acc[5] += mv * w1[1]; acc[6] += mv * w1[2]; acc[7] += mv * w1[3];
  }
  #pragma unroll
  for (int h = 0; h < 8; ++h) *(f32x4*)(&red[(w * 8 + h) * 256 + l * 4]) = acc[h];
  __syncthreads();
  float s8[8];
  #pragma unroll
  for (int h = 0; h < 8; ++h)
    s8[h] = red[h * 256 + t] + red[(8 + h) * 256 + t] + red[(16 + h) * 256 + t] +
            red[(24 + h) * 256 + t];
  uint4 u;
  u.x = f2bf(s8[0]) | ((unsigned)f2bf(s8[1]) << 16);
  u.y = f2bf(s8[2]) | ((unsigned)f2bf(s8[3]) << 16);
  u.z = f2bf(s8[4]) | ((unsigned)f2bf(s8[5]) << 16);
  u.w = f2bf(s8[6]) | ((unsigned)f2bf(s8[7]) << 16);
  *(uint4*)(wm_part + ((size_t)((b * 8 + blockIdx.x) * 256 + t)) * 8) = u;
}

// ---------------- kF: combine partials -> wa -> pack W'[b] = diag(wa)*output_w (bf16 frag)
__global__ void kF(const unsigned short* __restrict__ wm_part, const float* __restrict__ value_w,
                   const float* __restrict__ output_w, unsigned short* __restrict__ wpp) {
  int blk = blockIdx.x, t = threadIdx.x;
  int b = blk >> 2, quad = blk & 3;
  __shared__ float wml[8 * 256];
  __shared__ float wa[256];
  {
    float s8[8] = {0.f, 0.f, 0.f, 0.f, 0.f, 0.f, 0.f, 0.f};
    #pragma unroll
    for (int p = 0; p < 8; ++p) {
      uint4 u = *(const uint4*)(wm_part + ((size_t)((b * 8 + p) * 256 + t)) * 8);
      s8[0] += bf2f(u.x & 0xffff); s8[1] += bf2f(u.x >> 16);
      s8[2] += bf2f(u.y & 0xffff); s8[3] += bf2f(u.y >> 16);
      s8[4] += bf2f(u.z & 0xffff); s8[5] += bf2f(u.z >> 16);
      s8[6] += bf2f(u.w & 0xffff); s8[7] += bf2f(u.w >> 16);
    }
    #pragma unroll
    for (int h = 0; h < 8; ++h) wml[h * 256 + t] = s8[h];
  }
  __syncthreads();
  {
    int h = t >> 5, v = t & 31;
    float s = 0.f;
    #pragma unroll 4
    for (int d = 0; d < 256; ++d) s += wml[h * 256 + d] * value_w[d * 32 + v];
    wa[t] = s;
  }
  __syncthreads();
  unsigned short* wp = wpp + (size_t)b * 65536;
  int base = quad * 16384;
  for (int it = 0; it < 64; ++it) {
    int a = base + it * 256 + t;
    int sc = a >> 9, l = (a >> 3) & 63, j = a & 7;
    int s = sc >> 4, c = sc & 15, lh = l >> 4, ll = l & 15;
    int hv = s * 32 + lh * 8 + j, o = c * 16 + ll;
    wp[a] = f2bf(wa[hv] * output_w[hv * 256 + o]);
  }
}

// ---------------- kG: out = sigmoid(q@Wg+gb) @ W'[b] + ob   (64-row tiles, 256 thr)
__global__ void __launch_bounds__(256, 4) kG(
    const float* __restrict__ q_data, const float* __restrict__ gating_b,
    const float* __restrict__ output_b, const unsigned short* __restrict__ wgp,
    const unsigned short* __restrict__ wpp, float* __restrict__ out) {
  int b = blockIdx.y, row0 = blockIdx.x * 64, t = threadIdx.x;
  __shared__ __align__(16) unsigned char sG[64 * 528];
  {
    int w = t >> 6, d4 = t & 63;
    #pragma unroll
    for (int i = 0; i < 16; ++i) {
      int r = i * 4 + w;
      f32x4 v = *(const f32x4*)(q_data + ((size_t)(b * N_ + row0 + r)) * D_ + d4 * 4);
      uint2 pp;
      pp.x = f2bf(v[0]) | ((unsigned)f2bf(v[1]) << 16);
      pp.y = f2bf(v[2]) | ((unsigned)f2bf(v[3]) << 16);
      *(uint2*)(sG + r * 528 + d4 * 8) = pp;
    }
  }
  __syncthreads();
  int lane = t & 63, cg = t >> 6;
  int l15 = lane & 15, lhi = lane >> 4;
  const f32x4 z = {0.f, 0.f, 0.f, 0.f};
  f32x4 acc[16];
  #pragma unroll
  for (int f = 0; f < 16; ++f) acc[f] = z;
  const s16x8* Bg = (const s16x8*)wgp;
  #pragma unroll
  for (int s = 0; s < 8; ++s) {
    s16x8 af[4], bfr[4];
    #pragma unroll
    for (int rt = 0; rt < 4; ++rt)
      af[rt] = *(const s16x8*)(sG + (rt * 16 + l15) * 528 + s * 64 + lhi * 16);
    #pragma unroll
    for (int ct = 0; ct < 4; ++ct) bfr[ct] = Bg[(s * 16 + cg * 4 + ct) * 64 + lane];
    #pragma unroll
    for (int rt = 0; rt < 4; ++rt)
      #pragma unroll
      for (int ct = 0; ct < 4; ++ct)
        acc[rt * 4 + ct] =
            __builtin_amdgcn_mfma_f32_16x16x32_bf16(af[rt], bfr[ct], acc[rt * 4 + ct], 0, 0, 0);
  }
  __syncthreads();
  {
    float gb[4];
    #pragma unroll
    for (int ct = 0; ct < 4; ++ct) gb[ct] = gating_b[cg * 64 + ct * 16 + l15];
    #pragma unroll
    for (int rt = 0; rt < 4; ++rt)
      #pragma unroll
      for (int ct = 0; ct < 4; ++ct) {
        int col = cg * 64 + ct * 16 + l15;
        #pragma unroll
        for (int r = 0; r < 4; ++r) {
          float x = acc[rt * 4 + ct][r] + gb[ct];
          float g = 1.f / (1.f + __expf(-x));
          int row = rt * 16 + lhi * 4 + r;
          *(unsigned short*)(sG + row * 528 + col * 2) = f2bf(g);
        }
      }
  }
  __syncthreads();
  #pragma unroll
  for (int f = 0; f < 16; ++f) acc[f] = z;
  const s16x8* Bp = (const s16x8*)wpp + (size_t)b * 8192;
  #pragma unroll
  for (int s = 0; s < 8; ++s) {
    s16x8 af[4], bfr[4];
    #pragma unroll
    for (int rt = 0; rt < 4; ++rt)
      af[rt] = *(const s16x8*)(sG + (rt * 16 + l15) * 528 + s * 64 + lhi * 16);
    #pragma unroll
    for (int ct = 0; ct < 4; ++ct) bfr[ct] = Bp[(s * 16 + cg * 4 + ct) * 64 + lane];
    #pragma unroll
    for (int rt = 0; rt < 4; ++rt)
      #pragma unroll
      for (int ct = 0; ct < 4; ++ct)
        acc[rt * 4 + ct] =
            __builtin_amdgcn_mfma_f32_16x16x32_bf16(af[rt], bfr[ct], acc[rt * 4 + ct], 0, 0, 0);
  }
  __syncthreads();
  float* fOut = (float*)sG;
  float ob[4];
  #pragma unroll
  for (int ct = 0; ct < 4; ++ct) ob[ct] = output_b[cg * 64 + ct * 16 + l15];
  #pragma unroll
  for (int p = 0; p < 2; ++p) {
    #pragma unroll
    for (int rt2 = 0; rt2 < 2; ++rt2) {
      int rt = p * 2 + rt2;
      #pragma unroll
      for (int ct = 0; ct < 4; ++ct) {
        int col = cg * 64 + ct * 16 + l15;
        #pragma unroll
        for (int r = 0; r < 4; ++r)
          fOut[(rt2 * 16 + lhi * 4 + r) * 260 + col] = acc[rt * 4 + ct][r] + ob[ct];
      }
    }
    __syncthreads();
    {
      int w = t >> 6, c4 = t & 63;
      #pragma unroll
      for (int j = 0; j < 8; ++j) {
        int r32 = j * 4 + w;
        f32x4 v = *(const f32x4*)(fOut + r32 * 260 + c4 * 4);
        *(f32x4*)(out + ((size_t)(b * N_ + row0 + p * 32 + r32)) * D_ + c4 * 4) = v;
      }
    }
    __syncthreads();
  }
}

extern "C" void kernel_launch(void* const* d_in, const int* in_sizes, int n_in,
                              void* d_out, int out_size, void* d_ws, size_t ws_size,
                              hipStream_t stream) {
  const float* q_data   = (const float*)d_in[0];
  const float* m_data   = (const float*)d_in[1];
  const float* q_mask   = (const float*)d_in[2];
  const float* query_w  = (const float*)d_in[3];
  const float* key_w    = (const float*)d_in[4];
  const float* value_w  = (const float*)d_in[5];
  const float* gating_w = (const float*)d_in[6];
  const float* gating_b = (const float*)d_in[7];
  const float* output_w = (const float*)d_in[8];
  const float* output_b = (const float*)d_in[9];
  float* out = (float*)d_out;
  char* ws = (char*)d_ws;

  float* q_sum = (float*)(ws + WS_QSUM);
  float* msum  = (float*)(ws + WS_MSUM);
  unsigned short* qkbf = (unsigned short*)(ws + WS_QKBF);
  float* logits = (float*)(ws + WS_LOG);
  unsigned short* wmp = (unsigned short*)(ws + WS_WMP);
  unsigned short* wgp = (unsigned short*)(ws + WS_WGP);
  unsigned short* wpp = (unsigned short*)(ws + WS_WPP);

  hipMemsetAsync(d_ws, 0, WS_ZERO, stream);
  kA<<<576, 256, 0, stream>>>(q_data, q_mask, gating_w, q_sum, msum, wgp);
  kB<<<64, 256, 0, stream>>>(q_sum, msum, query_w, key_w, qkbf);
  kC<<<dim3(32, 64), 256, 0, stream>>>(m_data, q_mask, qkbf, logits);
  kS<<<64, 256, 0, stream>>>(logits);
  kE<<<dim3(8, 64), 256, 0, stream>>>(m_data, logits, wmp);
  kF<<<256, 256, 0, stream>>>(wmp, value_w, output_w, wpp);
  kG<<<dim3(32, 64), 256, 0, stream>>>(q_data, gating_b, output_b, wgp, wpp, out);
}